// Round 18
// baseline (103.283 us; speedup 1.0000x reference)
//
#include <hip/hip_runtime.h>
#include <math.h>

#define B_SZ   2048
#define D_SZ   4096
#define TB     16            // batch rows per block (8 pairs)
#define NC     16            // d-chunks (256 d per block)
#define DC     256           // d's per block (== blockDim)
#define NBG    (B_SZ / TB)   // 128 batch groups

typedef float v2f __attribute__((ext_vector_type(2)));

// ws layout: partial[NC][B_SZ][3] floats
#define WS_PART_BYTES  (NC * B_SZ * 3 * 4)

// ---------------------------------------------------------------------------
// DPP 4-lane-group sum: lane 3 (mod 4) holds its group's total.
template<int CTRL>
__device__ __forceinline__ float dpp_add(float v) {
    int x = __builtin_amdgcn_update_dpp(0, __float_as_int(v), CTRL, 0xF, 0xF, true);
    return v + __int_as_float(x);
}
__device__ __forceinline__ float group4_sum(float v) {
    v = dpp_add<0x111>(v);   // row_shr:1
    v = dpp_add<0x112>(v);   // row_shr:2
    return v;                // lanes 3,7,... hold their 4-lane group sum
}
__device__ __forceinline__ v2f pk_fma(v2f a, v2f b, v2f c) {
    return __builtin_elementwise_fma(a, b, c);
}
__device__ __forceinline__ v2f splat(float s) { v2f v = {s, s}; return v; }

// ---------------------------------------------------------------------------
// Fused kernel (R17 structure + occupancy push):
//  __launch_bounds__(256, 8): cap VGPR at 64 -> 8 waves/SIMD residency.
//  x loads software-pipelined one pair ahead (frees the xv[16] register block;
//  live set = cps[27] + ~8 v2f temps, fits the 64-reg budget without spill).
__global__ __launch_bounds__(256, 8) void kan_fused(
    const float* __restrict__ x, const float* __restrict__ grid_,
    const float* __restrict__ coef, const float* __restrict__ sb,
    const float* __restrict__ ssp,  const float* __restrict__ mask,
    float* __restrict__ partial)
{
    __shared__ float tl[64 * 49];          // 12.5 KB: [group g][sum sidx]

    const int tid = threadIdx.x;
    const int dc  = blockIdx.x;            // 0..NC-1 (x-fastest: contiguous x)
    const int bg  = blockIdx.y;            // 0..NBG-1
    const int d   = dc * DC + tid;
    const int lane = tid & 63;
    const int wv   = tid >> 6;

    const int b0 = bg * TB;
    const float* xp = x + (size_t)b0 * D_SZ + d;

    // ---- pipeline prologue: first x pair in flight under the conversion ----
    float xa = xp[0];
    float xb = xp[D_SZ];

    // ---- phase 1: fused basis conversion (once per thread, L2/L3-hot) ----
    float cps[27];
    #pragma unroll
    for (int o = 0; o < 3; ++o) {
        float m = mask[d*3 + o];
        float s = ssp[d*3 + o] * m;
        const float4* cvp = (const float4*)(coef + ((size_t)d*3 + o)*8);
        float4 ka = cvp[0], kb = cvp[1];
        float k[8] = {ka.x*s, ka.y*s, ka.z*s, ka.w*s,
                      kb.x*s, kb.y*s, kb.z*s, kb.w*s};
        float A3[5];                       // t^3 coef of cell c's local poly
        #pragma unroll
        for (int c = 0; c < 5; ++c)
            A3[c] = (k[c+3] - k[c] + 3.0f*(k[c+1] - k[c+2])) * (1.0f/6.0f);
        cps[0*3+o] = (k[0] + 4.0f*k[1] + k[2]) * (1.0f/6.0f);
        cps[1*3+o] = (k[2] - k[0]) * 0.5f;
        cps[2*3+o] = (k[0] + k[2]) * 0.5f - k[1];
        cps[3*3+o] = A3[0];
        cps[4*3+o] = A3[1] - A3[0];
        cps[5*3+o] = A3[2] - A3[1];
        cps[6*3+o] = A3[3] - A3[2];
        cps[7*3+o] = A3[4] - A3[3];
        cps[8*3+o] = sb[d*3 + o] * m;      // silu basis coef
    }

    const float g3   = grid_[3];                     // -1
    const float invh = 1.0f / (grid_[4] - grid_[3]); // 2.5
    const float c0   = -g3 * invh;
    const v2f invh2 = splat(invh);
    const v2f c0v = splat(c0);
    const v2f c1v = splat(c0 - 1.0f);
    const v2f c2v = splat(c0 - 2.0f);
    const v2f c3v = splat(c0 - 3.0f);
    const v2f c4v = splat(c0 - 4.0f);

    // silu polynomial constants (odd minimax/Taylor on [-1,1], |err|<=2.5e-5)
    const v2f pc7 = splat(-17.0f/80640.0f);
    const v2f pc5 = splat(1.0f/480.0f);
    const v2f pc3 = splat(-1.0f/48.0f);
    const v2f pc1 = splat(0.25f);

    // ---- phase 2: packed main loop, x pipelined one pair ahead ----
    #pragma unroll
    for (int pr = 0; pr < TB/2; ++pr) {
        float xa_n = 0.0f, xb_n = 0.0f;
        if (pr < TB/2 - 1) {               // issue next pair before computing
            xa_n = xp[(size_t)(2*pr + 2) * D_SZ];
            xb_n = xp[(size_t)(2*pr + 3) * D_SZ];
        }

        v2f X = {xa, xb};
        v2f u  = pk_fma(X, invh2, c0v);             // in [0,5)
        v2f u2 = u * u, u3 = u2 * u;
        v2f r1 = __builtin_elementwise_max(pk_fma(X, invh2, c1v), splat(0.0f));
        v2f r2 = __builtin_elementwise_max(pk_fma(X, invh2, c2v), splat(0.0f));
        v2f r3 = __builtin_elementwise_max(pk_fma(X, invh2, c3v), splat(0.0f));
        v2f r4 = __builtin_elementwise_max(pk_fma(X, invh2, c4v), splat(0.0f));
        v2f r13 = (r1*r1)*r1, r23 = (r2*r2)*r2, r33 = (r3*r3)*r3, r43 = (r4*r4)*r4;
        // silu(x) = x/2 + y*(1/4 + y*(-1/48 + y*(1/480 + y*(-17/80640)))), y=x^2
        v2f y  = X * X;
        v2f pt = pk_fma(y, pc7, pc5);
        pt = pk_fma(y, pt, pc3);
        pt = pk_fma(y, pt, pc1);
        v2f sil = pk_fma(y, pt, X * splat(0.5f));

        #pragma unroll
        for (int o = 0; o < 3; ++o) {
            // two independent 4-FMA halves (ILP), merged at the end
            v2f a0, a1;
            a0 = pk_fma(u,   splat(cps[1*3+o]), splat(cps[0*3+o]));
            a1 = pk_fma(r13, splat(cps[4*3+o]), sil * splat(cps[8*3+o]));
            a0 = pk_fma(u2,  splat(cps[2*3+o]), a0);
            a1 = pk_fma(r23, splat(cps[5*3+o]), a1);
            a0 = pk_fma(u3,  splat(cps[3*3+o]), a0);
            a1 = pk_fma(r33, splat(cps[6*3+o]), a1);
            a1 = pk_fma(r43, splat(cps[7*3+o]), a1);
            v2f a = a0 + a1;
            float sx = group4_sum(a.x);
            float sy = group4_sum(a.y);
            if ((lane & 3) == 3) {
                int g = wv*16 + (lane >> 2);       // 0..63
                tl[g*49 + (2*pr    )*3 + o] = sx;  // banks: (17g + s) % 32
                tl[g*49 + (2*pr + 1)*3 + o] = sy;  //  -> 16 writers, 16 banks
            }
        }
        xa = xa_n; xb = xb_n;
    }

    __syncthreads();
    if (tid < TB*3) {
        float s = 0.0f;
        #pragma unroll
        for (int g = 0; g < 64; ++g)       // fixed g: banks (17g+t)%32 distinct
            s += tl[g*49 + tid];
        int q = tid / 3, o = tid % 3;
        partial[((size_t)dc * B_SZ + (b0 + q))*3 + o] = s;
    }
}

// ---------------------------------------------------------------------------
__global__ __launch_bounds__(256) void reduce_partials(
    const float* __restrict__ partial, float* __restrict__ out)
{
    int i = blockIdx.x * 256 + threadIdx.x;
    if (i >= B_SZ * 3) return;
    float s = 0.0f;
    #pragma unroll
    for (int c = 0; c < NC; ++c) s += partial[(size_t)c * B_SZ * 3 + i];
    out[i] = s;
}

// ---------------------------------------------------------------------------
// Fallback (no workspace): block per b, raw arrays. Slower but correct.
__global__ __launch_bounds__(256) void kan_fallback(
    const float* __restrict__ x, const float* __restrict__ grid_,
    const float* __restrict__ coef, const float* __restrict__ sb,
    const float* __restrict__ ssp,  const float* __restrict__ mask,
    float* __restrict__ out)
{
    __shared__ float red[3][4];
    int b = blockIdx.x, tid = threadIdx.x;
    float g3 = grid_[3], invh = 1.0f / (grid_[4] - grid_[3]);
    float acc[3] = {0.f, 0.f, 0.f};
    for (int i = 0; i < D_SZ / 256; ++i) {
        int d = i * 256 + tid;
        float xv = x[(size_t)b * D_SZ + d];
        float u  = (xv - g3) * invh;
        float cfl = floorf(u);
        cfl = fminf(fmaxf(cfl, 0.0f), 4.0f);
        int  cell = (int)cfl;
        float t  = u - cfl;
        float t2 = t * t, t3 = t2 * t;
        float omt = 1.0f - t;
        float w0 = omt*omt*omt * (1.0f/6.0f);
        float w1 = (3.0f*t3 - 6.0f*t2 + 4.0f) * (1.0f/6.0f);
        float w2 = (-3.0f*t3 + 3.0f*t2 + 3.0f*t + 1.0f) * (1.0f/6.0f);
        float w3 = t3 * (1.0f/6.0f);
        float sil = xv / (1.0f + __expf(-xv));
        #pragma unroll
        for (int o = 0; o < 3; ++o) {
            const float* cp = &coef[(d*3 + o) * 8 + cell];
            float s = w0*cp[0] + w1*cp[1] + w2*cp[2] + w3*cp[3];
            float m = mask[d*3 + o];
            acc[o] += s * ssp[d*3 + o] * m + sil * sb[d*3 + o] * m;
        }
    }
    int lane = tid & 63, wv = tid >> 6;
    #pragma unroll
    for (int o = 0; o < 3; ++o) {
        float v = acc[o];
        #pragma unroll
        for (int off = 32; off >= 1; off >>= 1) v += __shfl_down(v, off, 64);
        if (lane == 0) red[o][wv] = v;
    }
    __syncthreads();
    if (tid < 3) {
        float s = red[tid][0] + red[tid][1] + red[tid][2] + red[tid][3];
        out[b * 3 + tid] = s;
    }
}

// ---------------------------------------------------------------------------
extern "C" void kernel_launch(void* const* d_in, const int* in_sizes, int n_in,
                              void* d_out, int out_size, void* d_ws, size_t ws_size,
                              hipStream_t stream)
{
    const float* x    = (const float*)d_in[0];
    const float* grid = (const float*)d_in[4];
    const float* coef = (const float*)d_in[5];
    const float* sb   = (const float*)d_in[6];
    const float* ssp  = (const float*)d_in[7];
    const float* mask = (const float*)d_in[8];
    float* out = (float*)d_out;

    if (ws_size >= (size_t)WS_PART_BYTES) {
        float* partial = (float*)d_ws;
        dim3 g(NC, NBG);                   // x = dc (16), y = bg (128)
        kan_fused<<<g, 256, 0, stream>>>(x, grid, coef, sb, ssp, mask, partial);
        reduce_partials<<<(B_SZ*3 + 255)/256, 256, 0, stream>>>(partial, out);
    } else {
        kan_fallback<<<B_SZ, 256, 0, stream>>>(x, grid, coef, sb, ssp, mask, out);
    }
}

// Round 19
// 52.297 us; speedup vs baseline: 1.9750x; 1.9750x over previous
//
#include <hip/hip_runtime.h>
#include <math.h>

#define B_SZ   2048
#define D_SZ   4096
#define TB     16            // batch rows per block (8 pairs)
#define NC     16            // d-chunks (256 d per block)
#define DC     256           // d's per block (== blockDim)
#define NBG    (B_SZ / TB)   // 128 batch groups

typedef float v2f __attribute__((ext_vector_type(2)));

// ws layout: partial[NC][B_SZ][3] floats
#define WS_PART_BYTES  (NC * B_SZ * 3 * 4)

// ---------------------------------------------------------------------------
// DPP 4-lane-group sum: lane 3 (mod 4) holds its group's total.
template<int CTRL>
__device__ __forceinline__ float dpp_add(float v) {
    int x = __builtin_amdgcn_update_dpp(0, __float_as_int(v), CTRL, 0xF, 0xF, true);
    return v + __int_as_float(x);
}
__device__ __forceinline__ float group4_sum(float v) {
    v = dpp_add<0x111>(v);   // row_shr:1
    v = dpp_add<0x112>(v);   // row_shr:2
    return v;                // lanes 3,7,... hold their 4-lane group sum
}
__device__ __forceinline__ v2f pk_fma(v2f a, v2f b, v2f c) {
    return __builtin_elementwise_fma(a, b, c);
}
__device__ __forceinline__ v2f splat(float s) { v2f v = {s, s}; return v; }

// ---------------------------------------------------------------------------
// Fused kernel (R17 structure; launch_bounds(256,6) -> VGPR cap 85, which the
// live-set (~cps27 + xv16 + ~30 temps) fits without spilling; 6 waves/SIMD):
__global__ __launch_bounds__(256, 6) void kan_fused(
    const float* __restrict__ x, const float* __restrict__ grid_,
    const float* __restrict__ coef, const float* __restrict__ sb,
    const float* __restrict__ ssp,  const float* __restrict__ mask,
    float* __restrict__ partial)
{
    __shared__ float tl[64 * 49];          // 12.5 KB: [group g][sum sidx]

    const int tid = threadIdx.x;
    const int dc  = blockIdx.x;            // 0..NC-1 (x-fastest: contiguous x)
    const int bg  = blockIdx.y;            // 0..NBG-1
    const int d   = dc * DC + tid;
    const int lane = tid & 63;
    const int wv   = tid >> 6;

    // ---- issue all 16 x loads up front (max memory-level parallelism) ----
    const int b0 = bg * TB;
    const float* xp = x + (size_t)b0 * D_SZ + d;
    float xv[TB];
    #pragma unroll
    for (int q = 0; q < TB; ++q) xv[q] = xp[(size_t)q * D_SZ];

    // ---- phase 1: fused basis conversion (once per thread, L2/L3-hot) ----
    float cps[27];
    #pragma unroll
    for (int o = 0; o < 3; ++o) {
        float m = mask[d*3 + o];
        float s = ssp[d*3 + o] * m;
        const float4* cvp = (const float4*)(coef + ((size_t)d*3 + o)*8);
        float4 ka = cvp[0], kb = cvp[1];
        float k[8] = {ka.x*s, ka.y*s, ka.z*s, ka.w*s,
                      kb.x*s, kb.y*s, kb.z*s, kb.w*s};
        float A3[5];                       // t^3 coef of cell c's local poly
        #pragma unroll
        for (int c = 0; c < 5; ++c)
            A3[c] = (k[c+3] - k[c] + 3.0f*(k[c+1] - k[c+2])) * (1.0f/6.0f);
        cps[0*3+o] = (k[0] + 4.0f*k[1] + k[2]) * (1.0f/6.0f);
        cps[1*3+o] = (k[2] - k[0]) * 0.5f;
        cps[2*3+o] = (k[0] + k[2]) * 0.5f - k[1];
        cps[3*3+o] = A3[0];
        cps[4*3+o] = A3[1] - A3[0];
        cps[5*3+o] = A3[2] - A3[1];
        cps[6*3+o] = A3[3] - A3[2];
        cps[7*3+o] = A3[4] - A3[3];
        cps[8*3+o] = sb[d*3 + o] * m;      // silu basis coef
    }

    const float g3   = grid_[3];                     // -1
    const float invh = 1.0f / (grid_[4] - grid_[3]); // 2.5
    const float c0   = -g3 * invh;
    const v2f invh2 = splat(invh);
    const v2f c0v = splat(c0);
    const v2f c1v = splat(c0 - 1.0f);
    const v2f c2v = splat(c0 - 2.0f);
    const v2f c3v = splat(c0 - 3.0f);
    const v2f c4v = splat(c0 - 4.0f);

    // silu polynomial constants (odd minimax/Taylor on [-1,1], |err|<=2.5e-5)
    const v2f pc7 = splat(-17.0f/80640.0f);
    const v2f pc5 = splat(1.0f/480.0f);
    const v2f pc3 = splat(-1.0f/48.0f);
    const v2f pc1 = splat(0.25f);

    // ---- phase 2: packed main loop (pairs of batch rows) ----
    #pragma unroll
    for (int pr = 0; pr < TB/2; ++pr) {
        v2f X = {xv[2*pr], xv[2*pr + 1]};
        v2f u  = pk_fma(X, invh2, c0v);             // in [0,5)
        v2f u2 = u * u, u3 = u2 * u;
        v2f r1 = __builtin_elementwise_max(pk_fma(X, invh2, c1v), splat(0.0f));
        v2f r2 = __builtin_elementwise_max(pk_fma(X, invh2, c2v), splat(0.0f));
        v2f r3 = __builtin_elementwise_max(pk_fma(X, invh2, c3v), splat(0.0f));
        v2f r4 = __builtin_elementwise_max(pk_fma(X, invh2, c4v), splat(0.0f));
        v2f r13 = (r1*r1)*r1, r23 = (r2*r2)*r2, r33 = (r3*r3)*r3, r43 = (r4*r4)*r4;
        // silu(x) = x/2 + y*(1/4 + y*(-1/48 + y*(1/480 + y*(-17/80640)))), y=x^2
        v2f y  = X * X;
        v2f pt = pk_fma(y, pc7, pc5);
        pt = pk_fma(y, pt, pc3);
        pt = pk_fma(y, pt, pc1);
        v2f sil = pk_fma(y, pt, X * splat(0.5f));

        #pragma unroll
        for (int o = 0; o < 3; ++o) {
            // two independent 4-FMA halves (ILP), merged at the end
            v2f a0, a1;
            a0 = pk_fma(u,   splat(cps[1*3+o]), splat(cps[0*3+o]));
            a1 = pk_fma(r13, splat(cps[4*3+o]), sil * splat(cps[8*3+o]));
            a0 = pk_fma(u2,  splat(cps[2*3+o]), a0);
            a1 = pk_fma(r23, splat(cps[5*3+o]), a1);
            a0 = pk_fma(u3,  splat(cps[3*3+o]), a0);
            a1 = pk_fma(r33, splat(cps[6*3+o]), a1);
            a1 = pk_fma(r43, splat(cps[7*3+o]), a1);
            v2f a = a0 + a1;
            float sx = group4_sum(a.x);
            float sy = group4_sum(a.y);
            if ((lane & 3) == 3) {
                int g = wv*16 + (lane >> 2);       // 0..63
                tl[g*49 + (2*pr    )*3 + o] = sx;  // banks: (17g + s) % 32
                tl[g*49 + (2*pr + 1)*3 + o] = sy;  //  -> 16 writers, 16 banks
            }
        }
    }

    __syncthreads();
    if (tid < TB*3) {
        float s = 0.0f;
        #pragma unroll
        for (int g = 0; g < 64; ++g)       // fixed g: banks (17g+t)%32 distinct
            s += tl[g*49 + tid];
        int q = tid / 3, o = tid % 3;
        partial[((size_t)dc * B_SZ + (b0 + q))*3 + o] = s;
    }
}

// ---------------------------------------------------------------------------
__global__ __launch_bounds__(256) void reduce_partials(
    const float* __restrict__ partial, float* __restrict__ out)
{
    int i = blockIdx.x * 256 + threadIdx.x;
    if (i >= B_SZ * 3) return;
    float s = 0.0f;
    #pragma unroll
    for (int c = 0; c < NC; ++c) s += partial[(size_t)c * B_SZ * 3 + i];
    out[i] = s;
}

// ---------------------------------------------------------------------------
// Fallback (no workspace): block per b, raw arrays. Slower but correct.
__global__ __launch_bounds__(256) void kan_fallback(
    const float* __restrict__ x, const float* __restrict__ grid_,
    const float* __restrict__ coef, const float* __restrict__ sb,
    const float* __restrict__ ssp,  const float* __restrict__ mask,
    float* __restrict__ out)
{
    __shared__ float red[3][4];
    int b = blockIdx.x, tid = threadIdx.x;
    float g3 = grid_[3], invh = 1.0f / (grid_[4] - grid_[3]);
    float acc[3] = {0.f, 0.f, 0.f};
    for (int i = 0; i < D_SZ / 256; ++i) {
        int d = i * 256 + tid;
        float xv = x[(size_t)b * D_SZ + d];
        float u  = (xv - g3) * invh;
        float cfl = floorf(u);
        cfl = fminf(fmaxf(cfl, 0.0f), 4.0f);
        int  cell = (int)cfl;
        float t  = u - cfl;
        float t2 = t * t, t3 = t2 * t;
        float omt = 1.0f - t;
        float w0 = omt*omt*omt * (1.0f/6.0f);
        float w1 = (3.0f*t3 - 6.0f*t2 + 4.0f) * (1.0f/6.0f);
        float w2 = (-3.0f*t3 + 3.0f*t2 + 3.0f*t + 1.0f) * (1.0f/6.0f);
        float w3 = t3 * (1.0f/6.0f);
        float sil = xv / (1.0f + __expf(-xv));
        #pragma unroll
        for (int o = 0; o < 3; ++o) {
            const float* cp = &coef[(d*3 + o) * 8 + cell];
            float s = w0*cp[0] + w1*cp[1] + w2*cp[2] + w3*cp[3];
            float m = mask[d*3 + o];
            acc[o] += s * ssp[d*3 + o] * m + sil * sb[d*3 + o] * m;
        }
    }
    int lane = tid & 63, wv = tid >> 6;
    #pragma unroll
    for (int o = 0; o < 3; ++o) {
        float v = acc[o];
        #pragma unroll
        for (int off = 32; off >= 1; off >>= 1) v += __shfl_down(v, off, 64);
        if (lane == 0) red[o][wv] = v;
    }
    __syncthreads();
    if (tid < 3) {
        float s = red[tid][0] + red[tid][1] + red[tid][2] + red[tid][3];
        out[b * 3 + tid] = s;
    }
}

// ---------------------------------------------------------------------------
extern "C" void kernel_launch(void* const* d_in, const int* in_sizes, int n_in,
                              void* d_out, int out_size, void* d_ws, size_t ws_size,
                              hipStream_t stream)
{
    const float* x    = (const float*)d_in[0];
    const float* grid = (const float*)d_in[4];
    const float* coef = (const float*)d_in[5];
    const float* sb   = (const float*)d_in[6];
    const float* ssp  = (const float*)d_in[7];
    const float* mask = (const float*)d_in[8];
    float* out = (float*)d_out;

    if (ws_size >= (size_t)WS_PART_BYTES) {
        float* partial = (float*)d_ws;
        dim3 g(NC, NBG);                   // x = dc (16), y = bg (128)
        kan_fused<<<g, 256, 0, stream>>>(x, grid, coef, sb, ssp, mask, partial);
        reduce_partials<<<(B_SZ*3 + 255)/256, 256, 0, stream>>>(partial, out);
    } else {
        kan_fallback<<<B_SZ, 256, 0, stream>>>(x, grid, coef, sb, ssp, mask, out);
    }
}

// Round 20
// 20.743 us; speedup vs baseline: 4.9792x; 2.5212x over previous
//
#include <hip/hip_runtime.h>
#include <math.h>

#define B_SZ   2048
#define D_SZ   4096
#define TB     16            // batch rows per block (8 pairs)
#define NC     16            // d-chunks (256 d per block)
#define DC     256           // d's per block (== blockDim)
#define NBG    (B_SZ / TB)   // 128 batch groups

typedef float v2f __attribute__((ext_vector_type(2)));

// ws layout: partial[NC][B_SZ][3] floats
#define WS_PART_BYTES  (NC * B_SZ * 3 * 4)

// ---------------------------------------------------------------------------
// DPP 4-lane-group sum: lane 3 (mod 4) holds its group's total.
template<int CTRL>
__device__ __forceinline__ float dpp_add(float v) {
    int x = __builtin_amdgcn_update_dpp(0, __float_as_int(v), CTRL, 0xF, 0xF, true);
    return v + __int_as_float(x);
}
__device__ __forceinline__ float group4_sum(float v) {
    v = dpp_add<0x111>(v);   // row_shr:1
    v = dpp_add<0x112>(v);   // row_shr:2
    return v;                // lanes 3,7,... hold their 4-lane group sum
}
__device__ __forceinline__ v2f pk_fma(v2f a, v2f b, v2f c) {
    return __builtin_elementwise_fma(a, b, c);
}
__device__ __forceinline__ v2f splat(float s) { v2f v = {s, s}; return v; }

// ---------------------------------------------------------------------------
// Fused kernel (best-measured configuration, R17 = 20.6 us):
//  - grid (x=dc, y=bg): concurrently-dispatched blocks sweep x contiguously
//  - phase 1: per-thread B-spline -> truncated-power basis conversion
//    {1,u,u2,u3,r1^3..r4^3,silu(x)} folded with ssp/sb/mask (27 regs)
//  - phase 2: packed-f32 (v_pk_fma) loop over 8 batch-row pairs; knot-folded
//    relus; silu via odd poly (|err|<=2.5e-5 on [-1,1]); split 4-FMA chains
//    for ILP; group4 DPP reduce into swizzled LDS (stride 49, conflict-free)
//  - natural register allocation (96 VGPR, 5 waves/SIMD): every forced cap
//    (64/40/32) spilled catastrophically (R3/R18/R19)
//  - cross-block reduce via second tiny kernel: in-kernel sync (atomics,
//    fences, cooperative) costs 50-170 us on MI355X (R10/R15/R16)
__global__ __launch_bounds__(256) void kan_fused(
    const float* __restrict__ x, const float* __restrict__ grid_,
    const float* __restrict__ coef, const float* __restrict__ sb,
    const float* __restrict__ ssp,  const float* __restrict__ mask,
    float* __restrict__ partial)
{
    __shared__ float tl[64 * 49];          // 12.5 KB: [group g][sum sidx]

    const int tid = threadIdx.x;
    const int dc  = blockIdx.x;            // 0..NC-1 (x-fastest: contiguous x)
    const int bg  = blockIdx.y;            // 0..NBG-1
    const int d   = dc * DC + tid;
    const int lane = tid & 63;
    const int wv   = tid >> 6;

    // ---- issue all 16 x loads up front (max memory-level parallelism) ----
    const int b0 = bg * TB;
    const float* xp = x + (size_t)b0 * D_SZ + d;
    float xv[TB];
    #pragma unroll
    for (int q = 0; q < TB; ++q) xv[q] = xp[(size_t)q * D_SZ];

    // ---- phase 1: fused basis conversion (once per thread, L2/L3-hot) ----
    float cps[27];
    #pragma unroll
    for (int o = 0; o < 3; ++o) {
        float m = mask[d*3 + o];
        float s = ssp[d*3 + o] * m;
        const float4* cvp = (const float4*)(coef + ((size_t)d*3 + o)*8);
        float4 ka = cvp[0], kb = cvp[1];
        float k[8] = {ka.x*s, ka.y*s, ka.z*s, ka.w*s,
                      kb.x*s, kb.y*s, kb.z*s, kb.w*s};
        float A3[5];                       // t^3 coef of cell c's local poly
        #pragma unroll
        for (int c = 0; c < 5; ++c)
            A3[c] = (k[c+3] - k[c] + 3.0f*(k[c+1] - k[c+2])) * (1.0f/6.0f);
        cps[0*3+o] = (k[0] + 4.0f*k[1] + k[2]) * (1.0f/6.0f);
        cps[1*3+o] = (k[2] - k[0]) * 0.5f;
        cps[2*3+o] = (k[0] + k[2]) * 0.5f - k[1];
        cps[3*3+o] = A3[0];
        cps[4*3+o] = A3[1] - A3[0];
        cps[5*3+o] = A3[2] - A3[1];
        cps[6*3+o] = A3[3] - A3[2];
        cps[7*3+o] = A3[4] - A3[3];
        cps[8*3+o] = sb[d*3 + o] * m;      // silu basis coef
    }

    const float g3   = grid_[3];                     // -1
    const float invh = 1.0f / (grid_[4] - grid_[3]); // 2.5
    const float c0   = -g3 * invh;
    const v2f invh2 = splat(invh);
    const v2f c0v = splat(c0);
    const v2f c1v = splat(c0 - 1.0f);
    const v2f c2v = splat(c0 - 2.0f);
    const v2f c3v = splat(c0 - 3.0f);
    const v2f c4v = splat(c0 - 4.0f);

    // silu polynomial constants (odd minimax/Taylor on [-1,1], |err|<=2.5e-5)
    const v2f pc7 = splat(-17.0f/80640.0f);
    const v2f pc5 = splat(1.0f/480.0f);
    const v2f pc3 = splat(-1.0f/48.0f);
    const v2f pc1 = splat(0.25f);

    // ---- phase 2: packed main loop (pairs of batch rows) ----
    #pragma unroll
    for (int pr = 0; pr < TB/2; ++pr) {
        v2f X = {xv[2*pr], xv[2*pr + 1]};
        v2f u  = pk_fma(X, invh2, c0v);             // in [0,5)
        v2f u2 = u * u, u3 = u2 * u;
        v2f r1 = __builtin_elementwise_max(pk_fma(X, invh2, c1v), splat(0.0f));
        v2f r2 = __builtin_elementwise_max(pk_fma(X, invh2, c2v), splat(0.0f));
        v2f r3 = __builtin_elementwise_max(pk_fma(X, invh2, c3v), splat(0.0f));
        v2f r4 = __builtin_elementwise_max(pk_fma(X, invh2, c4v), splat(0.0f));
        v2f r13 = (r1*r1)*r1, r23 = (r2*r2)*r2, r33 = (r3*r3)*r3, r43 = (r4*r4)*r4;
        // silu(x) = x/2 + y*(1/4 + y*(-1/48 + y*(1/480 + y*(-17/80640)))), y=x^2
        v2f y  = X * X;
        v2f pt = pk_fma(y, pc7, pc5);
        pt = pk_fma(y, pt, pc3);
        pt = pk_fma(y, pt, pc1);
        v2f sil = pk_fma(y, pt, X * splat(0.5f));

        #pragma unroll
        for (int o = 0; o < 3; ++o) {
            // two independent 4-FMA halves (ILP), merged at the end
            v2f a0, a1;
            a0 = pk_fma(u,   splat(cps[1*3+o]), splat(cps[0*3+o]));
            a1 = pk_fma(r13, splat(cps[4*3+o]), sil * splat(cps[8*3+o]));
            a0 = pk_fma(u2,  splat(cps[2*3+o]), a0);
            a1 = pk_fma(r23, splat(cps[5*3+o]), a1);
            a0 = pk_fma(u3,  splat(cps[3*3+o]), a0);
            a1 = pk_fma(r33, splat(cps[6*3+o]), a1);
            a1 = pk_fma(r43, splat(cps[7*3+o]), a1);
            v2f a = a0 + a1;
            float sx = group4_sum(a.x);
            float sy = group4_sum(a.y);
            if ((lane & 3) == 3) {
                int g = wv*16 + (lane >> 2);       // 0..63
                tl[g*49 + (2*pr    )*3 + o] = sx;  // banks: (17g + s) % 32
                tl[g*49 + (2*pr + 1)*3 + o] = sy;  //  -> 16 writers, 16 banks
            }
        }
    }

    __syncthreads();
    if (tid < TB*3) {
        float s = 0.0f;
        #pragma unroll
        for (int g = 0; g < 64; ++g)       // fixed g: banks (17g+t)%32 distinct
            s += tl[g*49 + tid];
        int q = tid / 3, o = tid % 3;
        partial[((size_t)dc * B_SZ + (b0 + q))*3 + o] = s;
    }
}

// ---------------------------------------------------------------------------
__global__ __launch_bounds__(256) void reduce_partials(
    const float* __restrict__ partial, float* __restrict__ out)
{
    int i = blockIdx.x * 256 + threadIdx.x;
    if (i >= B_SZ * 3) return;
    float s = 0.0f;
    #pragma unroll
    for (int c = 0; c < NC; ++c) s += partial[(size_t)c * B_SZ * 3 + i];
    out[i] = s;
}

// ---------------------------------------------------------------------------
// Fallback (no workspace): block per b, raw arrays. Slower but correct.
__global__ __launch_bounds__(256) void kan_fallback(
    const float* __restrict__ x, const float* __restrict__ grid_,
    const float* __restrict__ coef, const float* __restrict__ sb,
    const float* __restrict__ ssp,  const float* __restrict__ mask,
    float* __restrict__ out)
{
    __shared__ float red[3][4];
    int b = blockIdx.x, tid = threadIdx.x;
    float g3 = grid_[3], invh = 1.0f / (grid_[4] - grid_[3]);
    float acc[3] = {0.f, 0.f, 0.f};
    for (int i = 0; i < D_SZ / 256; ++i) {
        int d = i * 256 + tid;
        float xv = x[(size_t)b * D_SZ + d];
        float u  = (xv - g3) * invh;
        float cfl = floorf(u);
        cfl = fminf(fmaxf(cfl, 0.0f), 4.0f);
        int  cell = (int)cfl;
        float t  = u - cfl;
        float t2 = t * t, t3 = t2 * t;
        float omt = 1.0f - t;
        float w0 = omt*omt*omt * (1.0f/6.0f);
        float w1 = (3.0f*t3 - 6.0f*t2 + 4.0f) * (1.0f/6.0f);
        float w2 = (-3.0f*t3 + 3.0f*t2 + 3.0f*t + 1.0f) * (1.0f/6.0f);
        float w3 = t3 * (1.0f/6.0f);
        float sil = xv / (1.0f + __expf(-xv));
        #pragma unroll
        for (int o = 0; o < 3; ++o) {
            const float* cp = &coef[(d*3 + o) * 8 + cell];
            float s = w0*cp[0] + w1*cp[1] + w2*cp[2] + w3*cp[3];
            float m = mask[d*3 + o];
            acc[o] += s * ssp[d*3 + o] * m + sil * sb[d*3 + o] * m;
        }
    }
    int lane = tid & 63, wv = tid >> 6;
    #pragma unroll
    for (int o = 0; o < 3; ++o) {
        float v = acc[o];
        #pragma unroll
        for (int off = 32; off >= 1; off >>= 1) v += __shfl_down(v, off, 64);
        if (lane == 0) red[o][wv] = v;
    }
    __syncthreads();
    if (tid < 3) {
        float s = red[tid][0] + red[tid][1] + red[tid][2] + red[tid][3];
        out[b * 3 + tid] = s;
    }
}

// ---------------------------------------------------------------------------
extern "C" void kernel_launch(void* const* d_in, const int* in_sizes, int n_in,
                              void* d_out, int out_size, void* d_ws, size_t ws_size,
                              hipStream_t stream)
{
    const float* x    = (const float*)d_in[0];
    const float* grid = (const float*)d_in[4];
    const float* coef = (const float*)d_in[5];
    const float* sb   = (const float*)d_in[6];
    const float* ssp  = (const float*)d_in[7];
    const float* mask = (const float*)d_in[8];
    float* out = (float*)d_out;

    if (ws_size >= (size_t)WS_PART_BYTES) {
        float* partial = (float*)d_ws;
        dim3 g(NC, NBG);                   // x = dc (16), y = bg (128)
        kan_fused<<<g, 256, 0, stream>>>(x, grid, coef, sb, ssp, mask, partial);
        reduce_partials<<<(B_SZ*3 + 255)/256, 256, 0, stream>>>(partial, out);
    } else {
        kan_fallback<<<B_SZ, 256, 0, stream>>>(x, grid, coef, sb, ssp, mask, out);
    }
}